// Round 2
// baseline (806.053 us; speedup 1.0000x reference)
//
#include <hip/hip_runtime.h>

#define NTOK 64
#define DIM 192
#define HEADS 6
#define HD 32

typedef __attribute__((ext_vector_type(8))) short short8;
typedef __attribute__((ext_vector_type(4))) float floatx4;

__device__ __forceinline__ short f2bf(float f) {
    union { float f; unsigned int u; } c; c.f = f;
    unsigned int r = (c.u + 0x7FFFu + ((c.u >> 16) & 1u)) >> 16;
    return (short)(unsigned short)r;
}

// pack two fp32 -> two bf16 (round-half-up) in one dword: low16=bf(a), high16=bf(b)
__device__ __forceinline__ unsigned pkbf(float a, float b) {
    unsigned ua = __float_as_uint(a) + 0x8000u;
    unsigned ub = __float_as_uint(b) + 0x8000u;
    return __builtin_amdgcn_perm(ub, ua, 0x07060302u);
}
// 8 consecutive fp32 (16B-aligned) -> bf16x8 fragment (ascending k order)
__device__ __forceinline__ short8 cvt8(const float* p) {
    const float4* v = reinterpret_cast<const float4*>(p);
    float4 lo = v[0], hi = v[1];
    union { unsigned u[4]; short8 s; } r;
    r.u[0] = pkbf(lo.x, lo.y);
    r.u[1] = pkbf(lo.z, lo.w);
    r.u[2] = pkbf(hi.x, hi.y);
    r.u[3] = pkbf(hi.z, hi.w);
    return r.s;
}

// LDS strides (bf16 elems): RS=200 (100 dw == 4 mod 32), 72 (36 dw == 4 mod 32):
// ds_read_b128 over {16 rows x 4 quad-chunks} spreads 8 dwords/bank (b128 floor).
// All region sizes are multiples of 16B -> every b128 access stays 16B-aligned.
#define RS  200
#define VTS 72
#define PSS 72

__global__ __launch_bounds__(256, 1)
void wattn_fused(const float* __restrict__ x, const float* __restrict__ mask,
                 const float* __restrict__ wqkv, const float* __restrict__ wproj,
                 const float* __restrict__ bproj, float* __restrict__ out) {
    __shared__ short qs [NTOK * RS];   // q (token-major, bf16); reused for O before proj
    __shared__ short ksm[NTOK * RS];   // k (token-major, bf16)
    __shared__ short vsT[DIM  * VTS];  // v transposed: vsT[dim][token] (bf16)
    __shared__ short Ps [4 * 32 * PSS];// per-wave P scratch (D->A layout round-trip)

    const int bw   = blockIdx.x;
    const int tid  = (int)threadIdx.x;
    const int wave = tid >> 6;
    const int lane = tid & 63;
    const int r    = lane & 15;   // A: m-row / B: n-col / D: col
    const int quad = lane >> 4;   // A/B: k-group / D: row-group

    const float* xb = x + (size_t)bw * (NTOK * DIM);

    // ---------------- Phase 1: QKV = X * Wqkv^T ----------------
    // A-fragments of X in registers: A[m = mt*16 + r][k = s*32 + quad*8 + j]
    short8 a[4][6];
    #pragma unroll
    for (int mt = 0; mt < 4; ++mt) {
        #pragma unroll
        for (int s = 0; s < 6; ++s)
            a[mt][s] = cvt8(xb + (mt * 16 + r) * DIM + s * 32 + quad * 8);
    }

    const int W0 = wave * 144;  // each wave owns 144 of the 576 qkv columns
    #pragma unroll
    for (int nt = 0; nt < 9; ++nt) {
        const int d0 = W0 + nt * 16;
        floatx4 acc[4];
        #pragma unroll
        for (int mt = 0; mt < 4; ++mt) acc[mt] = (floatx4){0.f, 0.f, 0.f, 0.f};
        #pragma unroll
        for (int s = 0; s < 6; ++s) {
            // B[k=c][n=d] = Wqkv[d][c]: lane reads 8 contiguous fp32 of row d0+r
            short8 b = cvt8(wqkv + (d0 + r) * DIM + s * 32 + quad * 8);
            #pragma unroll
            for (int mt = 0; mt < 4; ++mt)
                acc[mt] = __builtin_amdgcn_mfma_f32_16x16x32_bf16(a[mt][s], b, acc[mt], 0, 0, 0);
        }
        // D layout: col = d0 + r, row = mt*16 + quad*4 + g  (uniform branch on d0)
        if (d0 < DIM) {                       // q: scale by 32^-0.5
            const int dc = d0 + r;
            #pragma unroll
            for (int mt = 0; mt < 4; ++mt) {
                #pragma unroll
                for (int g = 0; g < 4; ++g)
                    qs[(mt * 16 + quad * 4 + g) * RS + dc] =
                        f2bf(acc[mt][g] * 0.17677669529663688f);
            }
        } else if (d0 < 2 * DIM) {            // k
            const int dc = d0 - DIM + r;
            #pragma unroll
            for (int mt = 0; mt < 4; ++mt) {
                #pragma unroll
                for (int g = 0; g < 4; ++g)
                    ksm[(mt * 16 + quad * 4 + g) * RS + dc] = f2bf(acc[mt][g]);
            }
        } else {                              // v, stored transposed
            const int dc = d0 - 2 * DIM + r;
            #pragma unroll
            for (int mt = 0; mt < 4; ++mt) {
                #pragma unroll
                for (int g = 0; g < 4; ++g)
                    vsT[dc * VTS + (mt * 16 + quad * 4 + g)] = f2bf(acc[mt][g]);
            }
        }
    }
    __syncthreads();

    // ---------------- Phase 2: attention, unit = (head, query-half) ----------------
    const float* mb = mask + (size_t)bw * (NTOK * NTOK);
    short* pw = Ps + wave * (32 * PSS);
    float oreg[3][2][2][4];

    #pragma unroll
    for (int i = 0; i < 3; ++i) {
        const int uu   = wave * 3 + i;
        const int h    = uu >> 1;
        const int half = uu & 1;
        const int hc   = h * HD;

        // S = Q_half(32x32) * K^T(32x64)
        short8 aq[2], bk[4];
        #pragma unroll
        for (int mt = 0; mt < 2; ++mt)
            aq[mt] = *reinterpret_cast<const short8*>(
                qs + (half * 32 + mt * 16 + r) * RS + hc + quad * 8);
        #pragma unroll
        for (int nt = 0; nt < 4; ++nt)
            bk[nt] = *reinterpret_cast<const short8*>(
                ksm + (nt * 16 + r) * RS + hc + quad * 8);

        floatx4 sa[2][4];
        #pragma unroll
        for (int mt = 0; mt < 2; ++mt) {
            #pragma unroll
            for (int nt = 0; nt < 4; ++nt) {
                floatx4 z = (floatx4){0.f, 0.f, 0.f, 0.f};
                sa[mt][nt] = __builtin_amdgcn_mfma_f32_16x16x32_bf16(aq[mt], bk[nt], z, 0, 0, 0);
            }
        }

        // additive mask (fp32, coalesced along keys)
        #pragma unroll
        for (int mt = 0; mt < 2; ++mt) {
            #pragma unroll
            for (int g = 0; g < 4; ++g) {
                const int qt = half * 32 + mt * 16 + quad * 4 + g;
                #pragma unroll
                for (int nt = 0; nt < 4; ++nt)
                    sa[mt][nt][g] += mb[qt * NTOK + nt * 16 + r];
            }
        }

        // row softmax: in-lane over 4 n-tiles, then 16-lane (quad-internal) shfl reduce
        float rs_[2][4];
        #pragma unroll
        for (int mt = 0; mt < 2; ++mt) {
            #pragma unroll
            for (int g = 0; g < 4; ++g) {
                float m = fmaxf(fmaxf(sa[mt][0][g], sa[mt][1][g]),
                                fmaxf(sa[mt][2][g], sa[mt][3][g]));
                m = fmaxf(m, __shfl_xor(m, 1));
                m = fmaxf(m, __shfl_xor(m, 2));
                m = fmaxf(m, __shfl_xor(m, 4));
                m = fmaxf(m, __shfl_xor(m, 8));
                float sum = 0.f;
                #pragma unroll
                for (int nt = 0; nt < 4; ++nt) {
                    float p = __expf(sa[mt][nt][g] - m);
                    sa[mt][nt][g] = p;
                    sum += p;
                }
                sum += __shfl_xor(sum, 1);
                sum += __shfl_xor(sum, 2);
                sum += __shfl_xor(sum, 4);
                sum += __shfl_xor(sum, 8);
                rs_[mt][g] = sum;  // normalization deferred to after PV
            }
        }

        // P (unnormalized, in [0,1]) -> per-wave LDS scratch, row-major [query][key]
        #pragma unroll
        for (int mt = 0; mt < 2; ++mt) {
            #pragma unroll
            for (int g = 0; g < 4; ++g) {
                #pragma unroll
                for (int nt = 0; nt < 4; ++nt)
                    pw[(mt * 16 + quad * 4 + g) * PSS + nt * 16 + r] = f2bf(sa[mt][nt][g]);
            }
        }
        // same-wave LDS RAW: DS ops from one wave process in order; no barrier needed

        // O_half(32x32) = P(32x64) * V(64x32)
        floatx4 oa[2][2];
        #pragma unroll
        for (int mt = 0; mt < 2; ++mt) {
            #pragma unroll
            for (int nv = 0; nv < 2; ++nv) oa[mt][nv] = (floatx4){0.f, 0.f, 0.f, 0.f};
        }
        #pragma unroll
        for (int kk = 0; kk < 2; ++kk) {
            short8 bv[2], ap[2];
            #pragma unroll
            for (int nv = 0; nv < 2; ++nv)   // B[k=key][n=dim] from vsT rows (dim-major)
                bv[nv] = *reinterpret_cast<const short8*>(
                    vsT + (hc + nv * 16 + r) * VTS + kk * 32 + quad * 8);
            #pragma unroll
            for (int mt = 0; mt < 2; ++mt)
                ap[mt] = *reinterpret_cast<const short8*>(
                    pw + (mt * 16 + r) * PSS + kk * 32 + quad * 8);
            #pragma unroll
            for (int mt = 0; mt < 2; ++mt) {
                #pragma unroll
                for (int nv = 0; nv < 2; ++nv)
                    oa[mt][nv] = __builtin_amdgcn_mfma_f32_16x16x32_bf16(ap[mt], bv[nv], oa[mt][nv], 0, 0, 0);
            }
        }
        #pragma unroll
        for (int mt = 0; mt < 2; ++mt) {
            #pragma unroll
            for (int nv = 0; nv < 2; ++nv) {
                #pragma unroll
                for (int g = 0; g < 4; ++g)
                    oreg[i][mt][nv][g] = oa[mt][nv][g] / rs_[mt][g];
            }
        }
    }

    __syncthreads();  // everyone done reading qs/ksm/vsT

    // O -> qs region (bf16), token-major [t][h*32 + d]
    #pragma unroll
    for (int i = 0; i < 3; ++i) {
        const int uu = wave * 3 + i, h = uu >> 1, half = uu & 1;
        #pragma unroll
        for (int mt = 0; mt < 2; ++mt) {
            #pragma unroll
            for (int nv = 0; nv < 2; ++nv) {
                #pragma unroll
                for (int g = 0; g < 4; ++g)
                    qs[(half * 32 + mt * 16 + quad * 4 + g) * RS + h * HD + nv * 16 + r] =
                        f2bf(oreg[i][mt][nv][g]);
            }
        }
    }
    __syncthreads();

    // ---------------- Phase 3: out = O * Wproj^T + b ----------------
    short8 ao[4][6];
    #pragma unroll
    for (int mt = 0; mt < 4; ++mt) {
        #pragma unroll
        for (int s = 0; s < 6; ++s)
            ao[mt][s] = *reinterpret_cast<const short8*>(
                qs + (mt * 16 + r) * RS + s * 32 + quad * 8);
    }

    float* ob = out + (size_t)bw * (NTOK * DIM);
    const int D0 = wave * 48;  // 48 output cols per wave
    #pragma unroll
    for (int nt = 0; nt < 3; ++nt) {
        const int d0 = D0 + nt * 16;
        const float bias = bproj[d0 + r];
        floatx4 acc[4];
        #pragma unroll
        for (int mt = 0; mt < 4; ++mt) acc[mt] = (floatx4){bias, bias, bias, bias};
        #pragma unroll
        for (int s = 0; s < 6; ++s) {
            short8 b = cvt8(wproj + (d0 + r) * DIM + s * 32 + quad * 8);
            #pragma unroll
            for (int mt = 0; mt < 4; ++mt)
                acc[mt] = __builtin_amdgcn_mfma_f32_16x16x32_bf16(ao[mt][s], b, acc[mt], 0, 0, 0);
        }
        #pragma unroll
        for (int mt = 0; mt < 4; ++mt) {
            #pragma unroll
            for (int g = 0; g < 4; ++g)
                ob[(mt * 16 + quad * 4 + g) * DIM + d0 + r] = acc[mt][g];
        }
    }
}

extern "C" void kernel_launch(void* const* d_in, const int* in_sizes, int n_in,
                              void* d_out, int out_size, void* d_ws, size_t ws_size,
                              hipStream_t stream) {
    const float* x    = (const float*)d_in[0];
    const float* mask = (const float*)d_in[1];
    const float* wqkv = (const float*)d_in[2];
    const float* wp   = (const float*)d_in[3];
    const float* bp   = (const float*)d_in[4];
    float* out = (float*)d_out;
    const int nblocks = in_sizes[0] / (NTOK * DIM);  // 4096 windows
    wattn_fused<<<nblocks, 256, 0, stream>>>(x, mask, wqkv, wp, bp, out);
}

// Round 3
// 672.765 us; speedup vs baseline: 1.1981x; 1.1981x over previous
//
#include <hip/hip_runtime.h>

#define NTOK 64
#define DIM 192
#define HEADS 6
#define HD 32

typedef __attribute__((ext_vector_type(8))) short short8;
typedef __attribute__((ext_vector_type(4))) float floatx4;

__device__ __forceinline__ short f2bf(float f) {
    union { float f; unsigned int u; } c; c.f = f;
    unsigned int r = (c.u + 0x7FFFu + ((c.u >> 16) & 1u)) >> 16;
    return (short)(unsigned short)r;
}

// pack two fp32 -> two bf16 (round-half-up) in one dword: low16=bf(a), high16=bf(b)
__device__ __forceinline__ unsigned pkbf(float a, float b) {
    unsigned ua = __float_as_uint(a) + 0x8000u;
    unsigned ub = __float_as_uint(b) + 0x8000u;
    return __builtin_amdgcn_perm(ub, ua, 0x07060302u);
}
// 8 consecutive fp32 (16B-aligned) -> bf16x8 fragment (ascending k order)
__device__ __forceinline__ short8 cvt8(const float* p) {
    const float4* v = reinterpret_cast<const float4*>(p);
    float4 lo = v[0], hi = v[1];
    union { unsigned u[4]; short8 s; } r;
    r.u[0] = pkbf(lo.x, lo.y);
    r.u[1] = pkbf(lo.z, lo.w);
    r.u[2] = pkbf(hi.x, hi.y);
    r.u[3] = pkbf(hi.z, hi.w);
    return r.s;
}

// LDS strides (bf16 elems):
//   RS=200 (100 dw == 4 mod 32): b128 A/B reads spread 8 dw/bank (optimal).
//   VTS/PSS=68 (34 dw == 2 mod 32): b128 reads -> banks (2r+4q+p) = 8 dw/bank.
// Total LDS = 64*200*2 *2 + 192*68*2 = 77312 B <= 80KB -> 2 blocks/CU.
#define RS  200
#define VTS 68
#define PSS 68

__global__ __launch_bounds__(256, 2)
void wattn_fused(const float* __restrict__ x, const float* __restrict__ mask,
                 const float* __restrict__ wqkv, const float* __restrict__ wproj,
                 const float* __restrict__ bproj, float* __restrict__ out) {
    __shared__ short qs [NTOK * RS];   // q (token-major); then per-wave P scratch; then O
    __shared__ short ksm[NTOK * RS];   // k (token-major, bf16)
    __shared__ short vsT[DIM  * VTS];  // v transposed: vsT[dim][token] (bf16)

    const int bw   = blockIdx.x;
    const int tid  = (int)threadIdx.x;
    const int wave = tid >> 6;
    const int lane = tid & 63;
    const int r    = lane & 15;   // A: m-row / B: n-col / D: col
    const int quad = lane >> 4;   // A/B: k-group / D: row-group

    const float* xb = x + (size_t)bw * (NTOK * DIM);

    // ---------------- Phase 1: QKV = X * Wqkv^T ----------------
    // A-fragments of X in registers: A[m = mt*16 + r][k = s*32 + quad*8 + j]
    short8 a[4][6];
    #pragma unroll
    for (int mt = 0; mt < 4; ++mt) {
        #pragma unroll
        for (int s = 0; s < 6; ++s)
            a[mt][s] = cvt8(xb + (mt * 16 + r) * DIM + s * 32 + quad * 8);
    }

    const int W0 = wave * 144;  // each wave owns 144 of the 576 qkv columns
    #pragma unroll
    for (int nt = 0; nt < 9; ++nt) {
        const int d0 = W0 + nt * 16;
        floatx4 acc[4];
        #pragma unroll
        for (int mt = 0; mt < 4; ++mt) acc[mt] = (floatx4){0.f, 0.f, 0.f, 0.f};
        #pragma unroll
        for (int s = 0; s < 6; ++s) {
            // B[k=c][n=d] = Wqkv[d][c]: lane reads 8 contiguous fp32 of row d0+r
            short8 b = cvt8(wqkv + (d0 + r) * DIM + s * 32 + quad * 8);
            #pragma unroll
            for (int mt = 0; mt < 4; ++mt)
                acc[mt] = __builtin_amdgcn_mfma_f32_16x16x32_bf16(a[mt][s], b, acc[mt], 0, 0, 0);
        }
        // D layout: col = d0 + r, row = mt*16 + quad*4 + g  (uniform branch on d0)
        if (d0 < DIM) {                       // q: scale by 32^-0.5
            const int dc = d0 + r;
            #pragma unroll
            for (int mt = 0; mt < 4; ++mt) {
                #pragma unroll
                for (int g = 0; g < 4; ++g)
                    qs[(mt * 16 + quad * 4 + g) * RS + dc] =
                        f2bf(acc[mt][g] * 0.17677669529663688f);
            }
        } else if (d0 < 2 * DIM) {            // k
            const int dc = d0 - DIM + r;
            #pragma unroll
            for (int mt = 0; mt < 4; ++mt) {
                #pragma unroll
                for (int g = 0; g < 4; ++g)
                    ksm[(mt * 16 + quad * 4 + g) * RS + dc] = f2bf(acc[mt][g]);
            }
        } else {                              // v, stored transposed (g-consecutive -> b64)
            const int dc = d0 - 2 * DIM + r;
            #pragma unroll
            for (int mt = 0; mt < 4; ++mt) {
                #pragma unroll
                for (int g = 0; g < 4; ++g)
                    vsT[dc * VTS + (mt * 16 + quad * 4 + g)] = f2bf(acc[mt][g]);
            }
        }
    }
    __syncthreads();

    // ---------------- Phase 2: attention, unit = (head, query-half) ----------------
    const float* mb = mask + (size_t)bw * (NTOK * NTOK);
    short* pw = qs + wave * (32 * PSS);   // P scratch reuses the q region
    float oreg[3][2][2][4];

    // Preload ALL Q A-fragments for this wave's 3 units, then free qs for P scratch.
    short8 aq[3][2];
    #pragma unroll
    for (int i = 0; i < 3; ++i) {
        const int uu = wave * 3 + i, h = uu >> 1, half = uu & 1;
        #pragma unroll
        for (int mt = 0; mt < 2; ++mt)
            aq[i][mt] = *reinterpret_cast<const short8*>(
                qs + (half * 32 + mt * 16 + r) * RS + h * HD + quad * 8);
    }
    __syncthreads();   // Q fully consumed into registers across all waves

    #pragma unroll
    for (int i = 0; i < 3; ++i) {
        const int uu   = wave * 3 + i;
        const int h    = uu >> 1;
        const int half = uu & 1;
        const int hc   = h * HD;

        // S = Q_half(32x32) * K^T(32x64)
        short8 bk[4];
        #pragma unroll
        for (int nt = 0; nt < 4; ++nt)
            bk[nt] = *reinterpret_cast<const short8*>(
                ksm + (nt * 16 + r) * RS + hc + quad * 8);

        floatx4 sa[2][4];
        #pragma unroll
        for (int mt = 0; mt < 2; ++mt) {
            #pragma unroll
            for (int nt = 0; nt < 4; ++nt) {
                floatx4 z = (floatx4){0.f, 0.f, 0.f, 0.f};
                sa[mt][nt] = __builtin_amdgcn_mfma_f32_16x16x32_bf16(aq[i][mt], bk[nt], z, 0, 0, 0);
            }
        }

        // additive mask (fp32, coalesced along keys)
        #pragma unroll
        for (int mt = 0; mt < 2; ++mt) {
            #pragma unroll
            for (int g = 0; g < 4; ++g) {
                const int qt = half * 32 + mt * 16 + quad * 4 + g;
                #pragma unroll
                for (int nt = 0; nt < 4; ++nt)
                    sa[mt][nt][g] += mb[qt * NTOK + nt * 16 + r];
            }
        }

        // row softmax: in-lane over 4 n-tiles, then 16-lane shfl reduce
        float rs_[2][4];
        #pragma unroll
        for (int mt = 0; mt < 2; ++mt) {
            #pragma unroll
            for (int g = 0; g < 4; ++g) {
                float m = fmaxf(fmaxf(sa[mt][0][g], sa[mt][1][g]),
                                fmaxf(sa[mt][2][g], sa[mt][3][g]));
                m = fmaxf(m, __shfl_xor(m, 1));
                m = fmaxf(m, __shfl_xor(m, 2));
                m = fmaxf(m, __shfl_xor(m, 4));
                m = fmaxf(m, __shfl_xor(m, 8));
                float sum = 0.f;
                #pragma unroll
                for (int nt = 0; nt < 4; ++nt) {
                    float p = __expf(sa[mt][nt][g] - m);
                    sa[mt][nt][g] = p;
                    sum += p;
                }
                sum += __shfl_xor(sum, 1);
                sum += __shfl_xor(sum, 2);
                sum += __shfl_xor(sum, 4);
                sum += __shfl_xor(sum, 8);
                rs_[mt][g] = sum;  // normalization deferred to after PV
            }
        }

        // P (unnormalized, in [0,1]) -> per-wave LDS scratch, row-major [query][key]
        #pragma unroll
        for (int mt = 0; mt < 2; ++mt) {
            #pragma unroll
            for (int g = 0; g < 4; ++g) {
                #pragma unroll
                for (int nt = 0; nt < 4; ++nt)
                    pw[(mt * 16 + quad * 4 + g) * PSS + nt * 16 + r] = f2bf(sa[mt][nt][g]);
            }
        }
        // same-wave LDS RAW: DS ops from one wave complete in order via lgkmcnt

        // O_half(32x32) = P(32x64) * V(64x32)
        floatx4 oa[2][2];
        #pragma unroll
        for (int mt = 0; mt < 2; ++mt) {
            #pragma unroll
            for (int nv = 0; nv < 2; ++nv) oa[mt][nv] = (floatx4){0.f, 0.f, 0.f, 0.f};
        }
        #pragma unroll
        for (int kk = 0; kk < 2; ++kk) {
            short8 bv[2], ap[2];
            #pragma unroll
            for (int nv = 0; nv < 2; ++nv)   // B[k=key][n=dim] from vsT rows (dim-major)
                bv[nv] = *reinterpret_cast<const short8*>(
                    vsT + (hc + nv * 16 + r) * VTS + kk * 32 + quad * 8);
            #pragma unroll
            for (int mt = 0; mt < 2; ++mt)
                ap[mt] = *reinterpret_cast<const short8*>(
                    pw + (mt * 16 + r) * PSS + kk * 32 + quad * 8);
            #pragma unroll
            for (int mt = 0; mt < 2; ++mt) {
                #pragma unroll
                for (int nv = 0; nv < 2; ++nv)
                    oa[mt][nv] = __builtin_amdgcn_mfma_f32_16x16x32_bf16(ap[mt], bv[nv], oa[mt][nv], 0, 0, 0);
            }
        }
        #pragma unroll
        for (int mt = 0; mt < 2; ++mt) {
            #pragma unroll
            for (int nv = 0; nv < 2; ++nv) {
                #pragma unroll
                for (int g = 0; g < 4; ++g)
                    oreg[i][mt][nv][g] = oa[mt][nv][g] / rs_[mt][g];
            }
        }
    }

    __syncthreads();  // all P-scratch reads and ksm/vsT reads done

    // O -> qs region (bf16), token-major [t][h*32 + d]
    #pragma unroll
    for (int i = 0; i < 3; ++i) {
        const int uu = wave * 3 + i, h = uu >> 1, half = uu & 1;
        #pragma unroll
        for (int mt = 0; mt < 2; ++mt) {
            #pragma unroll
            for (int nv = 0; nv < 2; ++nv) {
                #pragma unroll
                for (int g = 0; g < 4; ++g)
                    qs[(half * 32 + mt * 16 + quad * 4 + g) * RS + h * HD + nv * 16 + r] =
                        f2bf(oreg[i][mt][nv][g]);
            }
        }
    }
    __syncthreads();

    // ---------------- Phase 3: out = O * Wproj^T + b ----------------
    short8 ao[4][6];
    #pragma unroll
    for (int mt = 0; mt < 4; ++mt) {
        #pragma unroll
        for (int s = 0; s < 6; ++s)
            ao[mt][s] = *reinterpret_cast<const short8*>(
                qs + (mt * 16 + r) * RS + s * 32 + quad * 8);
    }

    float* ob = out + (size_t)bw * (NTOK * DIM);
    const int D0 = wave * 48;  // 48 output cols per wave
    #pragma unroll
    for (int nt = 0; nt < 3; ++nt) {
        const int d0 = D0 + nt * 16;
        const float bias = bproj[d0 + r];
        floatx4 acc[4];
        #pragma unroll
        for (int mt = 0; mt < 4; ++mt) acc[mt] = (floatx4){bias, bias, bias, bias};
        #pragma unroll
        for (int s = 0; s < 6; ++s) {
            short8 b = cvt8(wproj + (d0 + r) * DIM + s * 32 + quad * 8);
            #pragma unroll
            for (int mt = 0; mt < 4; ++mt)
                acc[mt] = __builtin_amdgcn_mfma_f32_16x16x32_bf16(ao[mt][s], b, acc[mt], 0, 0, 0);
        }
        #pragma unroll
        for (int mt = 0; mt < 4; ++mt) {
            #pragma unroll
            for (int g = 0; g < 4; ++g)
                ob[(mt * 16 + quad * 4 + g) * DIM + d0 + r] = acc[mt][g];
        }
    }
}

extern "C" void kernel_launch(void* const* d_in, const int* in_sizes, int n_in,
                              void* d_out, int out_size, void* d_ws, size_t ws_size,
                              hipStream_t stream) {
    const float* x    = (const float*)d_in[0];
    const float* mask = (const float*)d_in[1];
    const float* wqkv = (const float*)d_in[2];
    const float* wp   = (const float*)d_in[3];
    const float* bp   = (const float*)d_in[4];
    float* out = (float*)d_out;
    const int nblocks = in_sizes[0] / (NTOK * DIM);  // 4096 windows
    wattn_fused<<<nblocks, 256, 0, stream>>>(x, mask, wqkv, wp, bp, out);
}